// Round 1
// baseline (208.258 us; speedup 1.0000x reference)
//
#include <hip/hip_runtime.h>
#include <math.h>
#include <stdlib.h>

// ---------------- constants ----------------
#define ECOMf 4.59925f
#define M0Bf  2.01026f
#define M0Cf  0.13957061f
#define M0Df  2.00685f

struct cf { float x, y; };
__device__ __forceinline__ cf cmul(const cf a, const cf b){ return {a.x*b.x - a.y*b.y, a.x*b.y + a.y*b.x}; }
__device__ __forceinline__ cf cmulr(const cf a, const float s){ return {a.x*s, a.y*s}; }
__device__ __forceinline__ cf cadd(const cf a, const cf b){ return {a.x+b.x, a.y+b.y}; }
__device__ __forceinline__ cf cconj(const cf a){ return {a.x, -a.y}; }

struct Consts {
  float zcF1[3][2];        // [r+1][i]  lsl0={(0,1),(2,1)}
  float zcF2[3][3][3];     // [p+1][w+1][i]  lsl1={(0,1),(2,1),(2,2)}
  float zc_q0rt, zc_q0nd, zc_q0bw;
  float d2F1[5][3][5];     // [r+2][f+1][i]  lsl0={(0,1),(2,1),(2,2),(2,3),(4,3)}
  float d2F2[3];           // [p+1]          lsl1={(2,1)}
  float d2_q0rt, d2_q0nd;
  float d1F1[3][3][3];     // [r+1][e+1][i]  lsl0={(0,1),(2,1),(2,2)}
  float d1F2[3][2];        // [w+1][i]       lsl1={(0,1),(2,1)}
  float d1_q0rt, d1_q0nd;
};

struct Ptrs { const float* p[28]; };

// ---------------- device helpers ----------------
__device__ __forceinline__ float getqf(float m, float m1, float m2){
  float ms = m1+m2, md = m1-m2;
  return sqrtf((m+ms)*(m-ms)*(m+md)*(m-md))/(2.f*m);
}
__device__ __forceinline__ float barrier2f(float z){ return 9.f + (3.f+z)*z; }
__device__ __forceinline__ float barrier4f(float z){ return z*(z*(z*(z+10.f)+135.f)+1575.f)+11025.f; }
__device__ __forceinline__ float rad2f(float q, float q0){
  float z = 9.f*q*q, z0 = 9.f*q0*q0;
  return q*q*sqrtf(barrier2f(z0)/barrier2f(z));
}
__device__ __forceinline__ float rad4f(float q, float q0){
  float z = 9.f*q*q, z0 = 9.f*q0*q0;
  float q2 = q*q;
  return q2*q2*sqrtf(barrier4f(z0)/barrier4f(z));
}
__device__ __forceinline__ cf epha(float a){  // exp(-i a)
  float s, c;
  __sincosf(a, &s, &c);
  return {c, -s};
}
__device__ __forceinline__ cf phm(const cf e, int im){  // e^m with m=im-1
  if (im == 1) { cf one = {1.f, 0.f}; return one; }
  if (im == 2) return e;
  return cconj(e);
}
// d^1 matrix, index [m1+1][m2+1]
__device__ __forceinline__ void d1mat(float cb, float d[3][3]){
  float A = sqrtf(fminf(1.f, fmaxf(0.f, 0.5f*(1.f+cb))));
  float B = sqrtf(fminf(1.f, fmaxf(0.f, 0.5f*(1.f-cb))));
  float AB = 1.4142135623730951f*A*B;
  float A2 = A*A, B2 = B*B;
  d[0][0]=A2;  d[0][1]=AB;     d[0][2]=B2;
  d[1][0]=-AB; d[1][1]=A2-B2;  d[1][2]=AB;
  d[2][0]=B2;  d[2][1]=-AB;    d[2][2]=A2;
}
// d^2 matrix, index [m1+2][m2+2]
__device__ __forceinline__ void d2mat(float cb, float d[5][5]){
  float A = sqrtf(fminf(1.f, fmaxf(0.f, 0.5f*(1.f+cb))));
  float B = sqrtf(fminf(1.f, fmaxf(0.f, 0.5f*(1.f-cb))));
  const float r6 = 2.449489742783178f;
  float A2=A*A, B2=B*B, A3=A2*A, B3=B2*B, A4=A2*A2, B4=B2*B2;
  float t  = A3*B - A*B3;     // AB*cosb
  float u  = A2*B2;
  d[0][0]=A4;        d[0][1]=2.f*A3*B;    d[0][2]=r6*u;          d[0][3]=2.f*A*B3;    d[0][4]=B4;
  d[1][0]=-2.f*A3*B; d[1][1]=A4-3.f*u;    d[1][2]=r6*t;          d[1][3]=3.f*u-B4;    d[1][4]=2.f*A*B3;
  d[2][0]=r6*u;      d[2][1]=-r6*t;       d[2][2]=A4-4.f*u+B4;   d[2][3]=r6*t;        d[2][4]=r6*u;
  d[3][0]=-2.f*A*B3; d[3][1]=3.f*u-B4;    d[3][2]=-r6*t;         d[3][3]=A4-3.f*u;    d[3][4]=2.f*A3*B;
  d[4][0]=B4;        d[4][1]=-2.f*A*B3;   d[4][2]=r6*u;          d[4][3]=-2.f*A3*B;   d[4][4]=A4;
}
__device__ __forceinline__ cf ldg(const float* __restrict__ gls, int i){
  cf r = { gls[2*i], gls[2*i+1] };
  return r;
}

// ---------------- kernel ----------------
__launch_bounds__(256, 2)
__global__ void amp_kernel(Ptrs P, Consts C, float* __restrict__ out, int N){
  int n = blockIdx.x * blockDim.x + threadIdx.x;
  float psum = 0.f;
  if (n < N) {
    const float* __restrict__ gls = P.p[27];

    cf amp[2][3][3];
    #pragma unroll
    for (int ia=0; ia<2; ++ia)
      #pragma unroll
      for (int ie=0; ie<3; ++ie)
        #pragma unroll
        for (int jf=0; jf<3; ++jf) { amp[ia][ie][jf].x = 0.f; amp[ia][ie][jf].y = 0.f; }

    //=========== Zc_4025 (ch=-1, Jr=1): BD chain ===========
    {
      const float m    = P.p[8][n];
      const float phiA = P.p[9][n];
      const float cosA = P.p[10][n];
      const float phiR = P.p[11][n];
      const float cosR = P.p[12][n];
      const float aB   = P.p[13][n];
      const float cbB  = P.p[14][n];
      const float gB   = P.p[15][n];
      const float aD   = P.p[16][n];
      const float cbD  = P.p[17][n];
      const float gD   = P.p[18][n];

      cf g0 = ldg(gls,0), g1 = ldg(gls,1), g2 = ldg(gls,2), g3 = ldg(gls,3), g4 = ldg(gls,4);

      float q_rt = getqf(ECOMf, M0Cf, m);
      float q_nd = getqf(m, M0Bf, M0Df);
      float r2rt = rad2f(q_rt, C.zc_q0rt);
      float r2nd = rad2f(q_nd, C.zc_q0nd);

      cf F1[3];
      #pragma unroll
      for (int ir=0; ir<3; ++ir)
        F1[ir] = cadd(cmulr(g0, C.zcF1[ir][0]), cmulr(g1, C.zcF1[ir][1]*r2rt));

      cf eDa = epha(aD);
      cf F2ph[3][3];
      #pragma unroll
      for (int ip=0; ip<3; ++ip)
        #pragma unroll
        for (int iw=0; iw<3; ++iw){
          cf t = cmulr(g2, C.zcF2[ip][iw][0]);
          t = cadd(t, cmulr(g3, C.zcF2[ip][iw][1]*r2nd));
          t = cadd(t, cmulr(g4, C.zcF2[ip][iw][2]*r2nd));
          F2ph[ip][iw] = cmul(t, phm(eDa, iw));
        }

      float dA[3][3], dR[3][3], dB[3][3], dD[3][3];
      d1mat(cosA, dA); d1mat(cosR, dR); d1mat(cbB, dB); d1mat(cbD, dD);

      cf eBa = epha(aB);
      cf DBph[3][3];
      #pragma unroll
      for (int ip=0; ip<3; ++ip){
        cf pp = phm(eBa, ip);
        #pragma unroll
        for (int ie=0; ie<3; ++ie)
          DBph[ip][ie] = cmulr(pp, dB[ip][ie]);
      }

      cf eR = epha(phiR);
      cf ampZ[2][3][3];
      #pragma unroll
      for (int ia=0; ia<2; ++ia)
        #pragma unroll
        for (int ie=0; ie<3; ++ie)
          #pragma unroll
          for (int jf=0; jf<3; ++jf) { ampZ[ia][ie][jf].x=0.f; ampZ[ia][ie][jf].y=0.f; }

      #pragma unroll
      for (int ir=0; ir<3; ++ir){
        cf Sr[3][3];
        #pragma unroll
        for (int ie=0; ie<3; ++ie)
          #pragma unroll
          for (int jf=0; jf<3; ++jf){ Sr[ie][jf].x=0.f; Sr[ie][jf].y=0.f; }

        #pragma unroll
        for (int ip=0; ip<3; ++ip){
          cf G[3];
          #pragma unroll
          for (int jf=0; jf<3; ++jf){ G[jf].x=0.f; G[jf].y=0.f; }
          #pragma unroll
          for (int iw=0; iw<3; ++iw){
            int k = ip - iw;       // p - w
            if (k >= -1 && k <= 1){
              cf t = cmulr(F2ph[ip][iw], dR[ir][k+1]);
              #pragma unroll
              for (int jf=0; jf<3; ++jf)
                G[jf] = cadd(G[jf], cmulr(t, dD[iw][jf]));
            }
          }
          #pragma unroll
          for (int ie=0; ie<3; ++ie)
            #pragma unroll
            for (int jf=0; jf<3; ++jf)
              Sr[ie][jf] = cadd(Sr[ie][jf], cmul(DBph[ip][ie], G[jf]));
        }
        cf Zr = cmul(F1[ir], phm(eR, ir));
        float dam = dA[0][ir], dap = dA[2][ir];
        #pragma unroll
        for (int ie=0; ie<3; ++ie)
          #pragma unroll
          for (int jf=0; jf<3; ++jf){
            cf zs = cmul(Zr, Sr[ie][jf]);
            ampZ[0][ie][jf] = cadd(ampZ[0][ie][jf], cmulr(zs, dam));
            ampZ[1][ie][jf] = cadd(ampZ[1][ie][jf], cmulr(zs, dap));
          }
      }

      // Breit-Wigner, L=0
      const float m0 = 4.026f, G0 = 0.025f;
      float width = G0 * (q_nd / C.zc_q0bw) * (m0 / m);
      float dre = m*m - m0*m0, dim_ = m0*width;
      float inv = 1.f/(dre*dre + dim_*dim_);
      cf bw = { dre*inv, -dim_*inv };

      cf eA = epha(phiA), eBg = epha(gB), eDg = epha(gD);
      #pragma unroll
      for (int ia=0; ia<2; ++ia){
        cf pa = cmul(bw, ia ? eA : cconj(eA));
        #pragma unroll
        for (int ie=0; ie<3; ++ie){
          cf pae = cmul(pa, phm(eBg, ie));
          #pragma unroll
          for (int jf=0; jf<3; ++jf){
            cf ph = cmul(pae, phm(eDg, jf));
            amp[ia][ie][jf] = cadd(amp[ia][ie][jf], cmul(ph, ampZ[ia][ie][jf]));
          }
        }
      }
    }

    //=========== D2_2460 (ch=1, Jr=2): BC chain ===========
    {
      const float m    = P.p[0][n];
      const float phiA = P.p[1][n];
      const float cosA = P.p[2][n];
      const float phiR = P.p[3][n];
      const float cosR = P.p[4][n];
      const float aB   = P.p[5][n];
      const float cbB  = P.p[6][n];
      const float gB   = P.p[7][n];

      cf g5 = ldg(gls,5), g6 = ldg(gls,6), g7 = ldg(gls,7), g8 = ldg(gls,8), g9 = ldg(gls,9), g10 = ldg(gls,10);

      float q_rt = getqf(ECOMf, M0Df, m);
      float q_nd = getqf(m, M0Bf, M0Cf);
      float r2rt = rad2f(q_rt, C.d2_q0rt);
      float r4rt = rad4f(q_rt, C.d2_q0rt);
      float r2nd = rad2f(q_nd, C.d2_q0nd);

      cf F1[5][3];
      #pragma unroll
      for (int ir=0; ir<5; ++ir)
        #pragma unroll
        for (int jf=0; jf<3; ++jf){
          cf t = cmulr(g5, C.d2F1[ir][jf][0]);
          t = cadd(t, cmulr(g6, C.d2F1[ir][jf][1]*r2rt));
          t = cadd(t, cmulr(g7, C.d2F1[ir][jf][2]*r2rt));
          t = cadd(t, cmulr(g8, C.d2F1[ir][jf][3]*r2rt));
          t = cadd(t, cmulr(g9, C.d2F1[ir][jf][4]*r4rt));
          F1[ir][jf] = t;
        }

      float dA[3][3], dB[3][3], dR2[5][5];
      d1mat(cosA, dA); d1mat(cbB, dB); d2mat(cosR, dR2);

      cf eBa = epha(aB);
      cf F2ph[3];
      #pragma unroll
      for (int ip=0; ip<3; ++ip)
        F2ph[ip] = cmul(cmulr(g10, C.d2F2[ip]*r2nd), phm(eBa, ip));

      cf W[5][3];
      #pragma unroll
      for (int ir=0; ir<5; ++ir)
        #pragma unroll
        for (int ie=0; ie<3; ++ie){ W[ir][ie].x=0.f; W[ir][ie].y=0.f; }
      #pragma unroll
      for (int ir=0; ir<5; ++ir)
        #pragma unroll
        for (int ip=0; ip<3; ++ip){
          cf t = cmulr(F2ph[ip], dR2[ir][ip+1]);
          #pragma unroll
          for (int ie=0; ie<3; ++ie)
            W[ir][ie] = cadd(W[ir][ie], cmulr(t, dB[ip][ie]));
        }

      cf eR = epha(phiR);
      cf eR2 = cmul(eR, eR);
      cf ampD[2][3][3];
      #pragma unroll
      for (int ia=0; ia<2; ++ia)
        #pragma unroll
        for (int ie=0; ie<3; ++ie)
          #pragma unroll
          for (int jf=0; jf<3; ++jf){ ampD[ia][ie][jf].x=0.f; ampD[ia][ie][jf].y=0.f; }

      #pragma unroll
      for (int ir=0; ir<5; ++ir){
        cf pr;
        if      (ir==0) pr = cconj(eR2);
        else if (ir==1) pr = cconj(eR);
        else if (ir==2) { pr.x=1.f; pr.y=0.f; }
        else if (ir==3) pr = eR;
        else            pr = eR2;
        #pragma unroll
        for (int jf=0; jf<3; ++jf){
          int k = (ir-2) - (jf-1);   // r - f
          if (k < -1 || k > 1) continue;
          cf Zrf = cmul(F1[ir][jf], pr);
          float dam = dA[0][k+1], dap = dA[2][k+1];
          #pragma unroll
          for (int ie=0; ie<3; ++ie){
            cf t = cmul(Zrf, W[ir][ie]);
            ampD[0][ie][jf] = cadd(ampD[0][ie][jf], cmulr(t, dam));
            ampD[1][ie][jf] = cadd(ampD[1][ie][jf], cmulr(t, dap));
          }
        }
      }

      // Breit-Wigner, L=2 (q = q_nd, q0 = d2_q0nd)
      const float m0 = 2.4607f, G0 = 0.0475f;
      float q0 = C.d2_q0nd;
      float z = 9.f*q_nd*q_nd, z0 = 9.f*q0*q0;
      float bpr2 = barrier2f(z0)/barrier2f(z);
      float qr = q_nd/q0;
      float width = G0 * qr*qr*qr*qr*qr * (m0/m) * bpr2;
      float dre = m*m - m0*m0, dim_ = m0*width;
      float inv = 1.f/(dre*dre + dim_*dim_);
      cf bw = { dre*inv, -dim_*inv };

      cf eA = epha(phiA), eBg = epha(gB);
      #pragma unroll
      for (int ia=0; ia<2; ++ia){
        cf pa = cmul(bw, ia ? eA : cconj(eA));
        #pragma unroll
        for (int ie=0; ie<3; ++ie){
          cf pae = cmul(pa, phm(eBg, ie));
          #pragma unroll
          for (int jf=0; jf<3; ++jf)
            amp[ia][ie][jf] = cadd(amp[ia][ie][jf], cmul(pae, ampD[ia][ie][jf]));
        }
      }
    }

    //=========== D1_2430 (ch=121, Jr=1): CD chain ===========
    {
      const float m    = P.p[19][n];
      const float phiA = P.p[20][n];
      const float cosA = P.p[21][n];
      const float phiR = P.p[22][n];
      const float cosR = P.p[23][n];
      const float aD   = P.p[24][n];
      const float cbD  = P.p[25][n];
      const float gD   = P.p[26][n];

      cf g11 = ldg(gls,11), g12 = ldg(gls,12), g13 = ldg(gls,13), g14 = ldg(gls,14), g15 = ldg(gls,15);

      float q_rt = getqf(ECOMf, M0Bf, m);
      float q_nd = getqf(m, M0Cf, M0Df);
      float r2rt = rad2f(q_rt, C.d1_q0rt);
      float r2nd = rad2f(q_nd, C.d1_q0nd);

      cf F1[3][3];
      #pragma unroll
      for (int ir=0; ir<3; ++ir)
        #pragma unroll
        for (int ie=0; ie<3; ++ie){
          cf t = cmulr(g11, C.d1F1[ir][ie][0]);
          t = cadd(t, cmulr(g12, C.d1F1[ir][ie][1]*r2rt));
          t = cadd(t, cmulr(g13, C.d1F1[ir][ie][2]*r2rt));
          F1[ir][ie] = t;
        }

      cf eDa = epha(aD);
      cf F2ph[3];
      #pragma unroll
      for (int iw=0; iw<3; ++iw){
        cf t = cadd(cmulr(g14, C.d1F2[iw][0]), cmulr(g15, C.d1F2[iw][1]*r2nd));
        F2ph[iw] = cmul(t, phm(eDa, iw));
      }

      float dA[3][3], dR[3][3], dD[3][3];
      d1mat(cosA, dA); d1mat(cosR, dR); d1mat(cbD, dD);

      cf G[3][3];
      #pragma unroll
      for (int ir=0; ir<3; ++ir)
        #pragma unroll
        for (int jf=0; jf<3; ++jf){ G[ir][jf].x=0.f; G[ir][jf].y=0.f; }
      #pragma unroll
      for (int ir=0; ir<3; ++ir)
        #pragma unroll
        for (int iw=0; iw<3; ++iw){
          cf t = cmulr(F2ph[iw], dR[ir][iw]);
          #pragma unroll
          for (int jf=0; jf<3; ++jf)
            G[ir][jf] = cadd(G[ir][jf], cmulr(t, dD[iw][jf]));
        }

      cf eR = epha(phiR);
      cf ampD[2][3][3];
      #pragma unroll
      for (int ia=0; ia<2; ++ia)
        #pragma unroll
        for (int ie=0; ie<3; ++ie)
          #pragma unroll
          for (int jf=0; jf<3; ++jf){ ampD[ia][ie][jf].x=0.f; ampD[ia][ie][jf].y=0.f; }

      #pragma unroll
      for (int ir=0; ir<3; ++ir){
        cf pr = phm(eR, ir);
        #pragma unroll
        for (int ie=0; ie<3; ++ie){
          int k = ir - ie;     // r - e
          if (k < -1 || k > 1) continue;
          cf Zre = cmul(F1[ir][ie], pr);
          float dam = dA[0][k+1], dap = dA[2][k+1];
          #pragma unroll
          for (int jf=0; jf<3; ++jf){
            cf t = cmul(Zre, G[ir][jf]);
            ampD[0][ie][jf] = cadd(ampD[0][ie][jf], cmulr(t, dam));
            ampD[1][ie][jf] = cadd(ampD[1][ie][jf], cmulr(t, dap));
          }
        }
      }

      // Breit-Wigner, L=0 (q = q_nd, q0 = d1_q0nd)
      const float m0 = 2.427f, G0 = 0.384f;
      float width = G0 * (q_nd / C.d1_q0nd) * (m0/m);
      float dre = m*m - m0*m0, dim_ = m0*width;
      float inv = 1.f/(dre*dre + dim_*dim_);
      cf bw = { dre*inv, -dim_*inv };

      cf eA = epha(phiA), eDg = epha(gD);
      #pragma unroll
      for (int ia=0; ia<2; ++ia){
        cf pa = cmul(bw, ia ? eA : cconj(eA));
        #pragma unroll
        for (int jf=0; jf<3; ++jf){
          cf paf = cmul(pa, phm(eDg, jf));
          #pragma unroll
          for (int ie=0; ie<3; ++ie)
            amp[ia][ie][jf] = cadd(amp[ia][ie][jf], cmul(paf, ampD[ia][ie][jf]));
        }
      }
    }

    #pragma unroll
    for (int ia=0; ia<2; ++ia)
      #pragma unroll
      for (int ie=0; ie<3; ++ie)
        #pragma unroll
        for (int jf=0; jf<3; ++jf)
          psum += amp[ia][ie][jf].x*amp[ia][ie][jf].x + amp[ia][ie][jf].y*amp[ia][ie][jf].y;
  }

  // wave + block reduction, one atomic per block
  #pragma unroll
  for (int off=32; off>0; off>>=1) psum += __shfl_down(psum, off, 64);
  __shared__ float red[4];
  int lane = threadIdx.x & 63, wid = threadIdx.x >> 6;
  if (lane == 0) red[wid] = psum;
  __syncthreads();
  if (threadIdx.x == 0) atomicAdd(out, red[0]+red[1]+red[2]+red[3]);
}

// ---------------- host-side constant generation ----------------
static double factd(int n){ double r=1.0; for (int i=2;i<=n;++i) r*=i; return r; }

static double cgc(int j1,int j2,int m1,int m2,int j,int m){
  if (m1+m2 != m || j < abs(j1-j2) || j > j1+j2) return 0.0;
  if (abs(m1)>j1 || abs(m2)>j2 || abs(m)>j) return 0.0;
  double pref = sqrt((2.0*j+1.0)*factd(j+j1-j2)*factd(j-j1+j2)*factd(j1+j2-j)/factd(j1+j2+j+1));
  pref *= sqrt(factd(j+m)*factd(j-m)*factd(j1-m1)*factd(j1+m1)*factd(j2-m2)*factd(j2+m2));
  double tot = 0.0;
  for (int k=0; k<=j1+j2-j; ++k){
    int d0=k, d1=j1+j2-j-k, d2=j1-m1-k, d3=j2+m2-k, d4=j-j2+m1+k, d5=j-j1-m2+k;
    if (d0<0||d1<0||d2<0||d3<0||d4<0||d5<0) continue;
    double p = factd(d0)*factd(d1)*factd(d2)*factd(d3)*factd(d4)*factd(d5);
    tot += ((k&1)? -1.0 : 1.0)/p;
  }
  return pref*tot;
}

static double getq_h(double m, double m1, double m2){
  double ms=m1+m2, md=m1-m2;
  return sqrt((m+ms)*(m-ms)*(m+md)*(m-md))/(2.0*m);
}

static void fill_consts(Consts& C){
  const double EC=4.59925, MB=2.01026, MC=0.13957061, MD=2.00685;
  // ---- Zc_4025: F1 (J1=1,J2=1,J3=0) lsl={(0,1),(2,1)} ----
  {
    const int ls0[2][2] = {{0,1},{2,1}};
    for (int ir=0; ir<3; ++ir){
      int r = ir-1;
      for (int i=0;i<2;++i){
        int l=ls0[i][0], s=ls0[i][1];
        C.zcF1[ir][i] = (float)( sqrt((2.0*l+1.0)/3.0)*cgc(1,0,r,0,s,r)*cgc(l,s,0,r,1,r) );
      }
    }
    const int ls1[3][2] = {{0,1},{2,1},{2,2}};
    for (int ip=0; ip<3; ++ip) for (int iw=0; iw<3; ++iw){
      int p=ip-1, w=iw-1;
      for (int i=0;i<3;++i){
        int l=ls1[i][0], s=ls1[i][1];
        C.zcF2[ip][iw][i] = (float)( sqrt((2.0*l+1.0)/3.0)*cgc(1,1,p,-w,s,p-w)*cgc(l,s,0,p-w,1,p-w) );
      }
    }
    C.zc_q0rt = (float)getq_h(EC, MC, 4.026);
    C.zc_q0nd = (float)getq_h(4.026, MB, MC);
    C.zc_q0bw = (float)getq_h(4.026, MB, MD);
  }
  // ---- D2_2460: F1 (J1=1,J2=2,J3=1) lsl={(0,1),(2,1),(2,2),(2,3),(4,3)} ----
  {
    const int ls0[5][2] = {{0,1},{2,1},{2,2},{2,3},{4,3}};
    for (int ir=0; ir<5; ++ir) for (int jf=0; jf<3; ++jf){
      int r=ir-2, f3=jf-1;
      for (int i=0;i<5;++i){
        int l=ls0[i][0], s=ls0[i][1];
        C.d2F1[ir][jf][i] = (float)( sqrt((2.0*l+1.0)/3.0)*cgc(2,1,r,-f3,s,r-f3)*cgc(l,s,0,r-f3,1,r-f3) );
      }
    }
    // F2 (J1=2,J2=1,J3=0) lsl={(2,1)}
    for (int ip=0; ip<3; ++ip){
      int p=ip-1;
      C.d2F2[ip] = (float)( sqrt(5.0/5.0)*cgc(1,0,p,0,1,p)*cgc(2,1,0,p,2,p) );
    }
    C.d2_q0rt = (float)getq_h(EC, MD, 2.4607);
    C.d2_q0nd = (float)getq_h(2.4607, MB, MC);
  }
  // ---- D1_2430: F1 (J1=1,J2=1,J3=1) lsl={(0,1),(2,1),(2,2)} ----
  {
    const int ls0[3][2] = {{0,1},{2,1},{2,2}};
    for (int ir=0; ir<3; ++ir) for (int ie=0; ie<3; ++ie){
      int r=ir-1, e=ie-1;
      for (int i=0;i<3;++i){
        int l=ls0[i][0], s=ls0[i][1];
        C.d1F1[ir][ie][i] = (float)( sqrt((2.0*l+1.0)/3.0)*cgc(1,1,r,-e,s,r-e)*cgc(l,s,0,r-e,1,r-e) );
      }
    }
    const int ls1[2][2] = {{0,1},{2,1}};
    for (int iw=0; iw<3; ++iw){
      int w=iw-1;
      for (int i=0;i<2;++i){
        int l=ls1[i][0], s=ls1[i][1];
        C.d1F2[iw][i] = (float)( sqrt((2.0*l+1.0)/3.0)*cgc(0,1,w,0,s,w)*cgc(l,s,0,w,1,w) );
      }
    }
    C.d1_q0rt = (float)getq_h(EC, MB, 2.427);
    C.d1_q0nd = (float)getq_h(2.427, MC, MD);
  }
}

// ---------------- launch ----------------
extern "C" void kernel_launch(void* const* d_in, const int* in_sizes, int n_in,
                              void* d_out, int out_size, void* d_ws, size_t ws_size,
                              hipStream_t stream){
  (void)n_in; (void)d_ws; (void)ws_size;
  Ptrs P;
  for (int i=0; i<28; ++i) P.p[i] = (const float*)d_in[i];
  Consts C;
  fill_consts(C);
  int N = in_sizes[0];
  hipMemsetAsync(d_out, 0, (size_t)out_size * sizeof(float), stream);
  int grid = (N + 255) / 256;
  amp_kernel<<<grid, 256, 0, stream>>>(P, C, (float*)d_out, N);
}